// Round 13
// baseline (60.208 us; speedup 1.0000x reference)
//
#include <hip/hip_runtime.h>

#define LQ    8500
#define C_DIM 256

typedef __attribute__((ext_vector_type(8))) short bf16x8;
typedef __attribute__((ext_vector_type(4))) float f32x4;

__device__ __forceinline__ unsigned short f2bf(float x) {
    union { float f; unsigned u; } c; c.f = x;
    unsigned r = c.u + 0x7FFFu + ((c.u >> 16) & 1u);
    return (unsigned short)(r >> 16);
}
__device__ __forceinline__ float bf2f(unsigned us) {
    union { unsigned u; float f; } c; c.u = us << 16;
    return c.f;
}

__device__ __forceinline__ void gload_lds16(const void* g, void* l) {
    __builtin_amdgcn_global_load_lds(
        (const __attribute__((address_space(1))) unsigned int*)g,
        (__attribute__((address_space(3))) unsigned int*)l, 16, 0, 0);
}

// ---------------------------------------------------------------------------
// prep: bf16-convert query & inflat (vectorized); transpose+convert weights
// to [N][K] bf16; concat off/attn weights (384 cols) and biases.
// ---------------------------------------------------------------------------
__global__ __launch_bounds__(256)
void prep_all(const float* __restrict__ query, const float* __restrict__ inflat,
              const float* __restrict__ Wv,   const float* __restrict__ Wout,
              const float* __restrict__ Woff, const float* __restrict__ Wattn,
              const float* __restrict__ boff, const float* __restrict__ battn,
              unsigned short* __restrict__ qbf,  unsigned short* __restrict__ ibf,
              unsigned short* __restrict__ Wv_t, unsigned short* __restrict__ Wout_t,
              unsigned short* __restrict__ Wcat_t, float* __restrict__ bcat)
{
    const int NV = LQ * 256 / 8;              // 272000 vec8 chunks per matrix
    const int tid    = blockIdx.x * 256 + threadIdx.x;
    const int stride = gridDim.x * 256;

    for (int v = tid; v < 2 * NV; v += stride) {
        const float*    src = (v < NV) ? query + (size_t)v * 8 : inflat + (size_t)(v - NV) * 8;
        unsigned short* dst = (v < NV) ? qbf   + (size_t)v * 8 : ibf    + (size_t)(v - NV) * 8;
        const float4 f0 = ((const float4*)src)[0];
        const float4 f1 = ((const float4*)src)[1];
        bf16x8 o;
        o[0] = (short)f2bf(f0.x); o[1] = (short)f2bf(f0.y);
        o[2] = (short)f2bf(f0.z); o[3] = (short)f2bf(f0.w);
        o[4] = (short)f2bf(f1.x); o[5] = (short)f2bf(f1.y);
        o[6] = (short)f2bf(f1.z); o[7] = (short)f2bf(f1.w);
        *(bf16x8*)dst = o;
    }

    const int total = 65536 * 3 + 32768 + 384;
    for (int i = tid; i < total; i += stride) {
        if (i < 65536) {
            int k = i >> 8, n = i & 255;
            Wv_t[n * 256 + k] = f2bf(Wv[i]);
        } else if (i < 131072) {
            int j = i - 65536; int k = j >> 8, n = j & 255;
            Wout_t[n * 256 + k] = f2bf(Wout[j]);
        } else if (i < 196608) {
            int j = i - 131072; int k = j >> 8, n = j & 255;
            Wcat_t[n * 256 + k] = f2bf(Woff[j]);
        } else if (i < 229376) {
            int j = i - 196608; int k = j >> 7, n = j & 127;
            Wcat_t[(256 + n) * 256 + k] = f2bf(Wattn[j]);
        } else {
            int j = i - 229376;
            bcat[j] = (j < 256) ? boff[j] : battn[j - 256];
        }
    }
}

// ---------------------------------------------------------------------------
// MFMA GEMM body (generic tile: 64 rows x (NJ*32) cols, BK=64, 256 threads =
// 4 waves as 2x2; each wave 32 rows x (NJ*16) cols). global_load_lds staging,
// XOR-swizzled source (LDS dest linear), swizzled ds_read_b128, double-
// buffered, 1 barrier per K-iter.
// OUTMODE: 1 = bf16 row-major, 2 = bf16 per-head planar
// ---------------------------------------------------------------------------
template<int OUTMODE, int NJ>
__device__ __forceinline__ void gemm_body(
    const unsigned short* __restrict__ A, const unsigned short* __restrict__ Bt,
    const float* __restrict__ bias, void* __restrict__ Out,
    int M, int N, int r0, int c0,
    char* As, char* Bs)
{
    const int t    = threadIdx.x;
    const int lane = t & 63, wave = t >> 6;
    const int wr   = wave >> 1, wc = wave & 1;
    const int lrow = lane & 15, lgrp = lane >> 4;
    constexpr int BROWS = NJ * 32;            // B tile rows (cols of Out)
    constexpr int BBUF  = BROWS * 128;        // bytes per B buffer

    f32x4 acc[2][NJ] = {};

    auto stage = [&](int buf, int k0) {
#pragma unroll
        for (int r = 0; r < 2; ++r) {
            const int row   = r * 32 + (t >> 3);
            const int chunk = (t & 7) ^ (row & 7);
            const unsigned short* g =
                A + (size_t)min(r0 + row, M - 1) * 256 + k0 + chunk * 8;
            gload_lds16(g, As + buf * 8192 + r * 4096 + wave * 1024);
        }
#pragma unroll
        for (int r = 0; r < BROWS / 32; ++r) {
            const int row   = r * 32 + (t >> 3);
            const int chunk = (t & 7) ^ (row & 7);
            const unsigned short* g = Bt + (size_t)(c0 + row) * 256 + k0 + chunk * 8;
            gload_lds16(g, Bs + buf * BBUF + r * 4096 + wave * 1024);
        }
    };

    auto compute = [&](int buf) {
#pragma unroll
        for (int kk = 0; kk < 2; ++kk) {
            const int g = kk * 4 + lgrp;
            bf16x8 a[2], b[NJ];
#pragma unroll
            for (int mi = 0; mi < 2; ++mi) {
                const int row = wr * 32 + mi * 16 + lrow;
                a[mi] = *(const bf16x8*)(As + buf * 8192 + row * 128 +
                                         ((g ^ (row & 7)) * 16));
            }
#pragma unroll
            for (int nj = 0; nj < NJ; ++nj) {
                const int row = wc * (NJ * 16) + nj * 16 + lrow;
                b[nj] = *(const bf16x8*)(Bs + buf * BBUF + row * 128 +
                                         ((g ^ (row & 7)) * 16));
            }
#pragma unroll
            for (int mi = 0; mi < 2; ++mi)
#pragma unroll
                for (int nj = 0; nj < NJ; ++nj)
                    acc[mi][nj] = __builtin_amdgcn_mfma_f32_16x16x32_bf16(
                        a[mi], b[nj], acc[mi][nj], 0, 0, 0);
        }
    };

    stage(0, 0);
    __syncthreads();
    int cur = 0;
#pragma unroll
    for (int it = 0; it < 3; ++it) {
        stage(cur ^ 1, (it + 1) * 64);
        compute(cur);
        __syncthreads();
        cur ^= 1;
    }
    compute(cur);

#pragma unroll
    for (int mi = 0; mi < 2; ++mi)
#pragma unroll
        for (int nj = 0; nj < NJ; ++nj) {
            const int col = c0 + wc * (NJ * 16) + nj * 16 + lrow;
            const float bb = bias[col];
#pragma unroll
            for (int j = 0; j < 4; ++j) {
                const int row = r0 + wr * 32 + mi * 16 + lgrp * 4 + j;
                if (row < M) {
                    const float v = acc[mi][nj][j] + bb;
                    if constexpr (OUTMODE == 1)
                        ((unsigned short*)Out)[(size_t)row * N + col] = f2bf(v);
                    else  // per-head planar: [h][row][ch]
                        ((unsigned short*)Out)[(size_t)(col >> 5) * (LQ * 32) +
                                               (size_t)row * 32 + (col & 31)] = f2bf(v);
                }
            }
        }
}

// fused value-proj (c<2, planar bf16) + off/attn-proj (c>=2, row-major bf16).
// 64x128 tiles: 1D grid 665 = 133 row-tiles x 5 col-tiles, XCD-chunked
// (bijective: nwg=665=8*83+1).
__global__ __launch_bounds__(256)
void gemm_dual(const unsigned short* __restrict__ A0, const unsigned short* __restrict__ B0,
               const float* __restrict__ bias0, unsigned short* __restrict__ out0,
               const unsigned short* __restrict__ A1, const unsigned short* __restrict__ B1,
               const float* __restrict__ bias1, unsigned short* __restrict__ out1)
{
    __shared__ __align__(16) char As[2 * 64 * 64 * 2];    // 16 KB
    __shared__ __align__(16) char Bs[2 * 128 * 64 * 2];   // 32 KB
    const int orig = blockIdx.x;
    const int xcd  = orig & 7, pos = orig >> 3;
    const int wgid = (xcd == 0 ? 0 : 84 + (xcd - 1) * 83) + pos;
    const int r0 = (wgid / 5) * 64;
    const int c  = wgid % 5;
    if (c < 2)
        gemm_body<2, 4>(A0, B0, bias0, out0, LQ, 256, r0, c * 128, As, Bs);
    else
        gemm_body<1, 4>(A1, B1, bias1, out1, LQ, 384, r0, (c - 2) * 128, As, Bs);
}

// ---------------------------------------------------------------------------
// Fused softmax + sampling + output projection. 512 threads, 16 queries/block.
// 4 iterations of the proven 128-thread/query sampling body (4 queries each,
// barrier-free, DPP quad broadcasts); msda rows land in LDS [16][264] bf16
// (528 B row stride = 132 words == 4 mod 32 banks -> 2-way, free); one
// barrier; then 8 waves do the M=16 out-projection with MFMA, B fragments
// read directly from L2-resident Wout_t. out never round-trips via HBM msda.
// ---------------------------------------------------------------------------
template<int J>
__device__ __forceinline__ void gather_j(const char* vb,
                                         const int* c_off, const float* c_w,
                                         float* a)
{
#pragma unroll
    for (int corner = 0; corner < 4; ++corner) {
        const int bo = __builtin_amdgcn_mov_dpp(c_off[corner], J * 0x55, 0xf, 0xf, 0);
        union { int i; float f; } uw;
        union { float f; int i; } sw; sw.f = c_w[corner];
        uw.i = __builtin_amdgcn_mov_dpp(sw.i, J * 0x55, 0xf, 0xf, 0);
        const float w = uw.f;
        const uint4 v = *(const uint4*)(vb + (size_t)(unsigned)bo);
        a[0] = fmaf(w, bf2f(v.x & 0xffffu), a[0]);
        a[1] = fmaf(w, bf2f(v.x >> 16), a[1]);
        a[2] = fmaf(w, bf2f(v.y & 0xffffu), a[2]);
        a[3] = fmaf(w, bf2f(v.y >> 16), a[3]);
        a[4] = fmaf(w, bf2f(v.z & 0xffffu), a[4]);
        a[5] = fmaf(w, bf2f(v.z >> 16), a[5]);
        a[6] = fmaf(w, bf2f(v.w & 0xffffu), a[6]);
        a[7] = fmaf(w, bf2f(v.w >> 16), a[7]);
    }
}

__global__ __launch_bounds__(512)
void msda_out(const unsigned short* __restrict__ value,   // planar bf16
              const unsigned short* __restrict__ offattn, // (LQ,384) bf16
              const float* __restrict__ refp,             // (LQ,4,2)
              const int*   __restrict__ shapes,           // (4,2)
              const int*   __restrict__ lstart,           // (4,)
              const unsigned short* __restrict__ Wout_t,  // (256,256) bf16 [n][k]
              const float* __restrict__ b_out,
              float* __restrict__ out)                    // (LQ,256) f32
{
    __shared__ __align__(16) char msda_lds[16 * 528];     // [16 rows][264 bf16]

    // XCD-chunked bijective swizzle: nwg=532=8*66+4
    const int orig = blockIdx.x;
    const int xcd  = orig & 7, pos = orig >> 3;
    const int wgid = (xcd < 4 ? xcd * 67 : 268 + (xcd - 4) * 66) + pos;
    const int q0 = wgid * 16;

    const int t   = threadIdx.x;
    const int grp = t >> 7, tl = t & 127;
    const int chunk = tl & 3, quarter = (tl >> 2) & 3, h = tl >> 4;

#pragma unroll
    for (int it = 0; it < 4; ++it) {
        const int qlocal = it * 4 + grp;
        const int q = min(q0 + qlocal, LQ - 1);

        // ---- per-combo: softmax + 4 corner (plane byte-offset, weight) ----
        int   c_off[4];
        float c_w[4];
        {
            const int lp = tl & 15, l = lp >> 2;
            const int Hs = shapes[2 * l + 0];
            const int Ws = shapes[2 * l + 1];
            const int st = lstart[l];

            const unsigned oxy = *(const unsigned*)(offattn + (size_t)q * 384 + 2 * tl);
            const float ox = bf2f(oxy & 0xffffu);
            const float oy = bf2f(oxy >> 16);
            const float rx = refp[q * 8 + l * 2 + 0];
            const float ry = refp[q * 8 + l * 2 + 1];

            const float x = (rx + ox / (float)Ws) * (float)Ws - 0.5f;
            const float y = (ry + oy / (float)Hs) * (float)Hs - 0.5f;
            const float x0f = floorf(x), y0f = floorf(y);
            const float lw = x - x0f, lh = y - y0f;
            const int   x0 = (int)x0f, y0 = (int)y0f;

            const float logit = bf2f(offattn[(size_t)q * 384 + 256 + tl]);
            float m = logit;
            for (int s = 8; s >= 1; s >>= 1) m = fmaxf(m, __shfl_xor(m, s, 16));
            const float e = __expf(logit - m);
            float ssum = e;
            for (int s = 8; s >= 1; s >>= 1) ssum += __shfl_xor(ssum, s, 16);
            const float a = e / ssum;

#pragma unroll
            for (int corner = 0; corner < 4; ++corner) {
                const int dy = corner >> 1, dx = corner & 1;
                const int hc = y0 + dy, wc = x0 + dx;
                const bool valid = (hc >= 0) && (hc < Hs) && (wc >= 0) && (wc < Ws);
                const float wy = dy ? lh : (1.f - lh);
                const float wx = dx ? lw : (1.f - lw);
                const int hcc = min(max(hc, 0), Hs - 1);
                const int wcc = min(max(wc, 0), Ws - 1);
                c_off[corner] = (st + hcc * Ws + wcc) * 64;   // plane bytes
                c_w[corner]   = valid ? (wy * wx * a) : 0.f;
            }
        }

        // ---- gather (quad-local data via DPP) ----
        const char* vb = (const char*)value + (size_t)h * (LQ * 64) + chunk * 16;
        float a[8] = {0.f, 0.f, 0.f, 0.f, 0.f, 0.f, 0.f, 0.f};
        gather_j<0>(vb, c_off, c_w, a);
        gather_j<1>(vb, c_off, c_w, a);
        gather_j<2>(vb, c_off, c_w, a);
        gather_j<3>(vb, c_off, c_w, a);

#pragma unroll
        for (int i = 0; i < 8; ++i) {
            a[i] += __shfl_xor(a[i], 4);
            a[i] += __shfl_xor(a[i], 8);
        }
        if (quarter == 0) {
            uint4 o;
            o.x = (unsigned)f2bf(a[0]) | ((unsigned)f2bf(a[1]) << 16);
            o.y = (unsigned)f2bf(a[2]) | ((unsigned)f2bf(a[3]) << 16);
            o.z = (unsigned)f2bf(a[4]) | ((unsigned)f2bf(a[5]) << 16);
            o.w = (unsigned)f2bf(a[6]) | ((unsigned)f2bf(a[7]) << 16);
            *(uint4*)(msda_lds + qlocal * 528 + h * 64 + chunk * 16) = o;
        }
    }
    __syncthreads();

    // ---- out[16 x 256] = msda @ Wout^T + b_out (8 waves x 32 cols) ----
    const int lane = t & 63, wave = t >> 6;
    const int lrow = lane & 15, lgrp = lane >> 4;
    const int c0 = wave * 32;

    f32x4 acc[2] = {};
#pragma unroll
    for (int ks = 0; ks < 8; ++ks) {
        const bf16x8 af = *(const bf16x8*)(msda_lds + lrow * 528 + ks * 64 + lgrp * 16);
#pragma unroll
        for (int nj = 0; nj < 2; ++nj) {
            const bf16x8 bf = *(const bf16x8*)(Wout_t +
                (size_t)(c0 + nj * 16 + lrow) * 256 + ks * 32 + lgrp * 8);
            acc[nj] = __builtin_amdgcn_mfma_f32_16x16x32_bf16(af, bf, acc[nj], 0, 0, 0);
        }
    }
#pragma unroll
    for (int nj = 0; nj < 2; ++nj) {
        const int col = c0 + nj * 16 + lrow;
        const float bb = b_out[col];
#pragma unroll
        for (int j = 0; j < 4; ++j) {
            const int q = q0 + lgrp * 4 + j;
            if (q < LQ) out[(size_t)q * 256 + col] = acc[nj][j] + bb;
        }
    }
}

// ---------------------------------------------------------------------------
extern "C" void kernel_launch(void* const* d_in, const int* in_sizes, int n_in,
                              void* d_out, int out_size, void* d_ws, size_t ws_size,
                              hipStream_t stream)
{
    const float* query  = (const float*)d_in[0];
    const float* refp   = (const float*)d_in[1];
    const float* inflat = (const float*)d_in[2];
    const int*   shapes = (const int*)  d_in[3];
    const int*   lstart = (const int*)  d_in[4];
    const float* W_off  = (const float*)d_in[5];
    const float* b_off  = (const float*)d_in[6];
    const float* W_attn = (const float*)d_in[7];
    const float* b_attn = (const float*)d_in[8];
    const float* W_v    = (const float*)d_in[9];
    const float* b_v    = (const float*)d_in[10];
    const float* W_out  = (const float*)d_in[11];
    const float* b_out  = (const float*)d_in[12];

    float* out = (float*)d_out;
    char*  ws  = (char*)d_ws;

    size_t o = 0;
    unsigned short* qbf    = (unsigned short*)(ws + o); o += (size_t)LQ * 256 * 2;
    unsigned short* ibf    = (unsigned short*)(ws + o); o += (size_t)LQ * 256 * 2;
    unsigned short* Wv_t   = (unsigned short*)(ws + o); o += 131072;
    unsigned short* Wout_t = (unsigned short*)(ws + o); o += 131072;
    unsigned short* Wcat_t = (unsigned short*)(ws + o); o += 196608;
    float*          bcat   = (float*)         (ws + o); o += 1536;
    unsigned short* value  = (unsigned short*)(ws + o); o += (size_t)LQ * 256 * 2;
    unsigned short* offattn= (unsigned short*)(ws + o); o += (size_t)LQ * 384 * 2;

    prep_all<<<1024, 256, 0, stream>>>(query, inflat, W_v, W_out, W_off, W_attn,
                                       b_off, b_attn, qbf, ibf,
                                       Wv_t, Wout_t, Wcat_t, bcat);

    gemm_dual<<<665, 256, 0, stream>>>(ibf, Wv_t, b_v, value,
                                       qbf, Wcat_t, bcat, offattn);

    msda_out<<<532, 512, 0, stream>>>(value, offattn, refp, shapes, lstart,
                                      Wout_t, b_out, out);
}

// Round 14
// 48.689 us; speedup vs baseline: 1.2366x; 1.2366x over previous
//
#include <hip/hip_runtime.h>

#define LQ    8500
#define C_DIM 256

typedef __attribute__((ext_vector_type(8))) short bf16x8;
typedef __attribute__((ext_vector_type(4))) float f32x4;

__device__ __forceinline__ unsigned short f2bf(float x) {
    union { float f; unsigned u; } c; c.f = x;
    unsigned r = c.u + 0x7FFFu + ((c.u >> 16) & 1u);
    return (unsigned short)(r >> 16);
}
__device__ __forceinline__ float bf2f(unsigned us) {
    union { unsigned u; float f; } c; c.u = us << 16;
    return c.f;
}

__device__ __forceinline__ void gload_lds16(const void* g, void* l) {
    __builtin_amdgcn_global_load_lds(
        (const __attribute__((address_space(1))) unsigned int*)g,
        (__attribute__((address_space(3))) unsigned int*)l, 16, 0, 0);
}

// ---------------------------------------------------------------------------
// prep: bf16-convert query & inflat (vectorized); transpose+convert weights
// to [N][K] bf16; concat off/attn weights (384 cols) and biases.
// ---------------------------------------------------------------------------
__global__ __launch_bounds__(256)
void prep_all(const float* __restrict__ query, const float* __restrict__ inflat,
              const float* __restrict__ Wv,   const float* __restrict__ Wout,
              const float* __restrict__ Woff, const float* __restrict__ Wattn,
              const float* __restrict__ boff, const float* __restrict__ battn,
              unsigned short* __restrict__ qbf,  unsigned short* __restrict__ ibf,
              unsigned short* __restrict__ Wv_t, unsigned short* __restrict__ Wout_t,
              unsigned short* __restrict__ Wcat_t, float* __restrict__ bcat)
{
    const int NV = LQ * 256 / 8;              // 272000 vec8 chunks per matrix
    const int tid    = blockIdx.x * 256 + threadIdx.x;
    const int stride = gridDim.x * 256;

    for (int v = tid; v < 2 * NV; v += stride) {
        const float*    src = (v < NV) ? query + (size_t)v * 8 : inflat + (size_t)(v - NV) * 8;
        unsigned short* dst = (v < NV) ? qbf   + (size_t)v * 8 : ibf    + (size_t)(v - NV) * 8;
        const float4 f0 = ((const float4*)src)[0];
        const float4 f1 = ((const float4*)src)[1];
        bf16x8 o;
        o[0] = (short)f2bf(f0.x); o[1] = (short)f2bf(f0.y);
        o[2] = (short)f2bf(f0.z); o[3] = (short)f2bf(f0.w);
        o[4] = (short)f2bf(f1.x); o[5] = (short)f2bf(f1.y);
        o[6] = (short)f2bf(f1.z); o[7] = (short)f2bf(f1.w);
        *(bf16x8*)dst = o;
    }

    const int total = 65536 * 3 + 32768 + 384;
    for (int i = tid; i < total; i += stride) {
        if (i < 65536) {
            int k = i >> 8, n = i & 255;
            Wv_t[n * 256 + k] = f2bf(Wv[i]);
        } else if (i < 131072) {
            int j = i - 65536; int k = j >> 8, n = j & 255;
            Wout_t[n * 256 + k] = f2bf(Wout[j]);
        } else if (i < 196608) {
            int j = i - 131072; int k = j >> 8, n = j & 255;
            Wcat_t[n * 256 + k] = f2bf(Woff[j]);
        } else if (i < 229376) {
            int j = i - 196608; int k = j >> 7, n = j & 127;
            Wcat_t[(256 + n) * 256 + k] = f2bf(Wattn[j]);
        } else {
            int j = i - 229376;
            bcat[j] = (j < 256) ? boff[j] : battn[j - 256];
        }
    }
}

// ---------------------------------------------------------------------------
// MFMA GEMM body (generic tile: 64 rows x (NJ*32) cols, BK=64, 256 threads =
// 4 waves as 2x2; each wave 32 rows x (NJ*16) cols). global_load_lds staging,
// XOR-swizzled source (LDS dest linear), swizzled ds_read_b128, double-
// buffered, 1 barrier per K-iter.
// NJ=2: 64x64 tile (As 8KB, Bs 8KB per buf). NJ=4: 64x128 (Bs 16KB per buf).
// OUTMODE: 0 = f32 row-major, 1 = bf16 row-major, 2 = bf16 per-head planar
//          (value layout: [h][row][32ch], plane stride LQ*32 elems)
// ---------------------------------------------------------------------------
template<int OUTMODE, int NJ>
__device__ __forceinline__ void gemm_body(
    const unsigned short* __restrict__ A, const unsigned short* __restrict__ Bt,
    const float* __restrict__ bias, void* __restrict__ Out,
    int M, int N, int r0, int c0,
    char* As, char* Bs)
{
    const int t    = threadIdx.x;
    const int lane = t & 63, wave = t >> 6;
    const int wr   = wave >> 1, wc = wave & 1;
    const int lrow = lane & 15, lgrp = lane >> 4;
    constexpr int BROWS = NJ * 32;            // B tile rows (cols of Out)
    constexpr int BBUF  = BROWS * 128;        // bytes per B buffer

    f32x4 acc[2][NJ] = {};

    auto stage = [&](int buf, int k0) {
#pragma unroll
        for (int r = 0; r < 2; ++r) {
            const int row   = r * 32 + (t >> 3);
            const int chunk = (t & 7) ^ (row & 7);
            const unsigned short* g =
                A + (size_t)min(r0 + row, M - 1) * 256 + k0 + chunk * 8;
            gload_lds16(g, As + buf * 8192 + r * 4096 + wave * 1024);
        }
#pragma unroll
        for (int r = 0; r < BROWS / 32; ++r) {
            const int row   = r * 32 + (t >> 3);
            const int chunk = (t & 7) ^ (row & 7);
            const unsigned short* g = Bt + (size_t)(c0 + row) * 256 + k0 + chunk * 8;
            gload_lds16(g, Bs + buf * BBUF + r * 4096 + wave * 1024);
        }
    };

    auto compute = [&](int buf) {
#pragma unroll
        for (int kk = 0; kk < 2; ++kk) {
            const int g = kk * 4 + lgrp;
            bf16x8 a[2], b[NJ];
#pragma unroll
            for (int mi = 0; mi < 2; ++mi) {
                const int row = wr * 32 + mi * 16 + lrow;
                a[mi] = *(const bf16x8*)(As + buf * 8192 + row * 128 +
                                         ((g ^ (row & 7)) * 16));
            }
#pragma unroll
            for (int nj = 0; nj < NJ; ++nj) {
                const int row = wc * (NJ * 16) + nj * 16 + lrow;
                b[nj] = *(const bf16x8*)(Bs + buf * BBUF + row * 128 +
                                         ((g ^ (row & 7)) * 16));
            }
#pragma unroll
            for (int mi = 0; mi < 2; ++mi)
#pragma unroll
                for (int nj = 0; nj < NJ; ++nj)
                    acc[mi][nj] = __builtin_amdgcn_mfma_f32_16x16x32_bf16(
                        a[mi], b[nj], acc[mi][nj], 0, 0, 0);
        }
    };

    stage(0, 0);
    __syncthreads();
    int cur = 0;
#pragma unroll
    for (int it = 0; it < 3; ++it) {
        stage(cur ^ 1, (it + 1) * 64);
        compute(cur);
        __syncthreads();
        cur ^= 1;
    }
    compute(cur);

#pragma unroll
    for (int mi = 0; mi < 2; ++mi)
#pragma unroll
        for (int nj = 0; nj < NJ; ++nj) {
            const int col = c0 + wc * (NJ * 16) + nj * 16 + lrow;
            const float bb = bias[col];
#pragma unroll
            for (int j = 0; j < 4; ++j) {
                const int row = r0 + wr * 32 + mi * 16 + lgrp * 4 + j;
                if (row < M) {
                    const float v = acc[mi][nj][j] + bb;
                    if constexpr (OUTMODE == 0)
                        ((float*)Out)[(size_t)row * N + col] = v;
                    else if constexpr (OUTMODE == 1)
                        ((unsigned short*)Out)[(size_t)row * N + col] = f2bf(v);
                    else  // per-head planar: [h][row][ch]
                        ((unsigned short*)Out)[(size_t)(col >> 5) * (LQ * 32) +
                                               (size_t)row * 32 + (col & 31)] = f2bf(v);
                }
            }
        }
}

// fused value-proj (c<2, planar bf16) + off/attn-proj (c>=2, row-major bf16).
// 64x128 tiles: 1D grid 665 = 133 row-tiles x 5 col-tiles, row-major in wgid,
// XCD-chunked (bijective: nwg=665=8*83+1) so a row-tile's 5 col-blocks share
// one XCD's L2 -> A-tile L2 re-reads halved vs 64x64.
__global__ __launch_bounds__(256)
void gemm_dual(const unsigned short* __restrict__ A0, const unsigned short* __restrict__ B0,
               const float* __restrict__ bias0, unsigned short* __restrict__ out0,
               const unsigned short* __restrict__ A1, const unsigned short* __restrict__ B1,
               const float* __restrict__ bias1, unsigned short* __restrict__ out1)
{
    __shared__ __align__(16) char As[2 * 64 * 64 * 2];    // 16 KB
    __shared__ __align__(16) char Bs[2 * 128 * 64 * 2];   // 32 KB
    const int orig = blockIdx.x;
    const int xcd  = orig & 7, pos = orig >> 3;
    const int wgid = (xcd == 0 ? 0 : 84 + (xcd - 1) * 83) + pos;
    const int r0 = (wgid / 5) * 64;
    const int c  = wgid % 5;
    if (c < 2)
        gemm_body<2, 4>(A0, B0, bias0, out0, LQ, 256, r0, c * 128, As, Bs);
    else
        gemm_body<1, 4>(A1, B1, bias1, out1, LQ, 384, r0, (c - 2) * 128, As, Bs);
}

// out-GEMM: 64x64 tiles, 1D grid 532 = 133 row-tiles x 4 col-tiles,
// XCD-chunked (nwg=532=8*66+4).
__global__ __launch_bounds__(256)
void gemm_f32out(const unsigned short* __restrict__ A, const unsigned short* __restrict__ Bt,
                 const float* __restrict__ bias, float* __restrict__ out)
{
    __shared__ __align__(16) char As[2 * 64 * 64 * 2];
    __shared__ __align__(16) char Bs[2 * 64 * 64 * 2];
    const int orig = blockIdx.x;
    const int xcd  = orig & 7, pos = orig >> 3;
    const int wgid = (xcd < 4 ? xcd * 67 : 268 + (xcd - 4) * 66) + pos;
    gemm_body<0, 2>(A, Bt, bias, out, LQ, 256, (wgid >> 2) * 64, (wgid & 3) * 64,
                    As, Bs);
}

// ---------------------------------------------------------------------------
// Fused softmax + deformable bilinear sampling — barrier-free, LDS-free.
// Each thread computes its own combo's (offset, weight) for 4 corners, then
// the gather phase pulls the quad's 4 combos via DPP quad_perm broadcasts
// (pure VALU, no LDS pipe, no __syncthreads). XCD-chunked block swizzle.
// value is per-head planar [h][LEN_IN][32ch] bf16 (64 B rows).
// ---------------------------------------------------------------------------
template<int J>
__device__ __forceinline__ void gather_j(const char* vb,
                                         const int* c_off, const float* c_w,
                                         float* a)
{
#pragma unroll
    for (int corner = 0; corner < 4; ++corner) {
        // broadcast lane (quad_base + J)'s offset/weight to the whole quad
        const int bo = __builtin_amdgcn_mov_dpp(c_off[corner], J * 0x55, 0xf, 0xf, 0);
        union { int i; float f; } uw;
        union { float f; int i; } sw; sw.f = c_w[corner];
        uw.i = __builtin_amdgcn_mov_dpp(sw.i, J * 0x55, 0xf, 0xf, 0);
        const float w = uw.f;
        const uint4 v = *(const uint4*)(vb + (size_t)(unsigned)bo);
        a[0] = fmaf(w, bf2f(v.x & 0xffffu), a[0]);
        a[1] = fmaf(w, bf2f(v.x >> 16), a[1]);
        a[2] = fmaf(w, bf2f(v.y & 0xffffu), a[2]);
        a[3] = fmaf(w, bf2f(v.y >> 16), a[3]);
        a[4] = fmaf(w, bf2f(v.z & 0xffffu), a[4]);
        a[5] = fmaf(w, bf2f(v.z >> 16), a[5]);
        a[6] = fmaf(w, bf2f(v.w & 0xffffu), a[6]);
        a[7] = fmaf(w, bf2f(v.w >> 16), a[7]);
    }
}

__global__ __launch_bounds__(256)
void msda_sample(const unsigned short* __restrict__ value,   // planar bf16
                 const unsigned short* __restrict__ offattn, // (LQ,384) bf16
                 const float* __restrict__ refp,             // (LQ,4,2)
                 const int*   __restrict__ shapes,           // (4,2)
                 const int*   __restrict__ lstart,           // (4,)
                 unsigned short* __restrict__ msda)          // (LQ,256) bf16
{
    // bijective XCD-chunk swizzle: nwg=4250, q=531, r=2 (m204 variant)
    const int orig = blockIdx.x;
    const int xcd  = orig & 7, pos = orig >> 3;
    const int wgid = (xcd < 2 ? xcd * 532 : 1064 + (xcd - 2) * 531) + pos;

    const int t   = threadIdx.x;
    const int sub = t >> 7, tl = t & 127;
    const int q   = wgid * 2 + sub;

    // ---- per-combo: softmax + 4 corner (plane byte-offset, weight) ----
    int   c_off[4];
    float c_w[4];
    {
        const int lp = tl & 15, l = lp >> 2;
        const int Hs = shapes[2 * l + 0];
        const int Ws = shapes[2 * l + 1];
        const int st = lstart[l];

        const unsigned oxy = *(const unsigned*)(offattn + (size_t)q * 384 + 2 * tl);
        const float ox = bf2f(oxy & 0xffffu);
        const float oy = bf2f(oxy >> 16);
        const float rx = refp[q * 8 + l * 2 + 0];
        const float ry = refp[q * 8 + l * 2 + 1];

        const float x = (rx + ox / (float)Ws) * (float)Ws - 0.5f;
        const float y = (ry + oy / (float)Hs) * (float)Hs - 0.5f;
        const float x0f = floorf(x), y0f = floorf(y);
        const float lw = x - x0f, lh = y - y0f;
        const int   x0 = (int)x0f, y0 = (int)y0f;

        const float logit = bf2f(offattn[(size_t)q * 384 + 256 + tl]);
        float m = logit;
        for (int s = 8; s >= 1; s >>= 1) m = fmaxf(m, __shfl_xor(m, s, 16));
        const float e = __expf(logit - m);
        float ssum = e;
        for (int s = 8; s >= 1; s >>= 1) ssum += __shfl_xor(ssum, s, 16);
        const float a = e / ssum;

#pragma unroll
        for (int corner = 0; corner < 4; ++corner) {
            const int dy = corner >> 1, dx = corner & 1;
            const int hc = y0 + dy, wc = x0 + dx;
            const bool valid = (hc >= 0) && (hc < Hs) && (wc >= 0) && (wc < Ws);
            const float wy = dy ? lh : (1.f - lh);
            const float wx = dx ? lw : (1.f - lw);
            const int hcc = min(max(hc, 0), Hs - 1);
            const int wcc = min(max(wc, 0), Ws - 1);
            c_off[corner] = (st + hcc * Ws + wcc) * 64;   // plane byte offset
            c_w[corner]   = valid ? (wy * wx * a) : 0.f;
        }
    }

    // ---- gather phase (same thread, quad-local data via DPP) ----
    const int chunk = tl & 3, quarter = (tl >> 2) & 3, h = tl >> 4;
    const char* vb = (const char*)value + (size_t)h * (LQ * 64) + chunk * 16;
    float a[8] = {0.f, 0.f, 0.f, 0.f, 0.f, 0.f, 0.f, 0.f};
    gather_j<0>(vb, c_off, c_w, a);
    gather_j<1>(vb, c_off, c_w, a);
    gather_j<2>(vb, c_off, c_w, a);
    gather_j<3>(vb, c_off, c_w, a);

#pragma unroll
    for (int i = 0; i < 8; ++i) {
        a[i] += __shfl_xor(a[i], 4);
        a[i] += __shfl_xor(a[i], 8);
    }
    if (quarter == 0) {
        uint4 o;
        o.x = (unsigned)f2bf(a[0]) | ((unsigned)f2bf(a[1]) << 16);
        o.y = (unsigned)f2bf(a[2]) | ((unsigned)f2bf(a[3]) << 16);
        o.z = (unsigned)f2bf(a[4]) | ((unsigned)f2bf(a[5]) << 16);
        o.w = (unsigned)f2bf(a[6]) | ((unsigned)f2bf(a[7]) << 16);
        *(uint4*)(msda + (size_t)q * 256 + h * 32 + chunk * 8) = o;
    }
}

// ---------------------------------------------------------------------------
extern "C" void kernel_launch(void* const* d_in, const int* in_sizes, int n_in,
                              void* d_out, int out_size, void* d_ws, size_t ws_size,
                              hipStream_t stream)
{
    const float* query  = (const float*)d_in[0];
    const float* refp   = (const float*)d_in[1];
    const float* inflat = (const float*)d_in[2];
    const int*   shapes = (const int*)  d_in[3];
    const int*   lstart = (const int*)  d_in[4];
    const float* W_off  = (const float*)d_in[5];
    const float* b_off  = (const float*)d_in[6];
    const float* W_attn = (const float*)d_in[7];
    const float* b_attn = (const float*)d_in[8];
    const float* W_v    = (const float*)d_in[9];
    const float* b_v    = (const float*)d_in[10];
    const float* W_out  = (const float*)d_in[11];
    const float* b_out  = (const float*)d_in[12];

    float* out = (float*)d_out;
    char*  ws  = (char*)d_ws;

    size_t o = 0;
    unsigned short* qbf    = (unsigned short*)(ws + o); o += (size_t)LQ * 256 * 2;
    unsigned short* ibf    = (unsigned short*)(ws + o); o += (size_t)LQ * 256 * 2;
    unsigned short* Wv_t   = (unsigned short*)(ws + o); o += 131072;
    unsigned short* Wout_t = (unsigned short*)(ws + o); o += 131072;
    unsigned short* Wcat_t = (unsigned short*)(ws + o); o += 196608;
    float*          bcat   = (float*)         (ws + o); o += 1536;
    unsigned short* value  = (unsigned short*)(ws + o); o += (size_t)LQ * 256 * 2;
    unsigned short* offattn= (unsigned short*)(ws + o); o += (size_t)LQ * 384 * 2;
    unsigned short* msda   = (unsigned short*)(ws + o);

    prep_all<<<1024, 256, 0, stream>>>(query, inflat, W_v, W_out, W_off, W_attn,
                                       b_off, b_attn, qbf, ibf,
                                       Wv_t, Wout_t, Wcat_t, bcat);

    gemm_dual<<<665, 256, 0, stream>>>(ibf, Wv_t, b_v, value,
                                       qbf, Wcat_t, bcat, offattn);

    msda_sample<<<4250, 256, 0, stream>>>(value, offattn, refp, shapes, lstart, msda);

    gemm_f32out<<<532, 256, 0, stream>>>(msda, Wout_t, b_out, out);
}